// Round 6
// baseline (255.602 us; speedup 1.0000x reference)
//
#include <hip/hip_runtime.h>
#include <hip/hip_bf16.h>
#include <stdint.h>

// Problem constants
#define BATCH 64
#define CHN 3
#define HH 224
#define WW 224
#define PIX (HH * WW)          // 50176
#define NSEG 196
#define MAXP 400
#define KDIM (CHN * MAXP)      // 1200
#define DN 768

#define KP4 1216               // K in u32 hi/lo pairs per row (padded)
#define NTK 38                 // 1216 / 32 K-steps
#define MROWS (BATCH * NSEG)   // 12544

// chunking for stable rank assignment
#define CHSZ 512
#define NCH (PIX / CHSZ)       // 98

typedef short short8 __attribute__((ext_vector_type(8)));
typedef float f32x16 __attribute__((ext_vector_type(16)));
typedef unsigned int uint4v __attribute__((ext_vector_type(4)));

// K permutation: k = c*MAXP + r -> kappa = 3r + c (scatter writes one dwordx3
// per pixel). Applied to BOTH A and W; dot product invariant.

// pack fp32 -> (bf16_hi << 16) | bf16_lo  with hi = rn(v), lo = rn(v - hi)
// As a bf16x2 word: (elem0=lo, elem1=hi). Raw MFMA gives lo*lo'+hi*hi';
// vs rot16'd B gives lo*hi'+hi*lo' -> 2 passes = exact 4-term product.
__device__ __forceinline__ uint32_t packhl(float v) {
    uint32_t x = __float_as_uint(v);
    uint32_t hi = (x + 0x7FFFu + ((x >> 16) & 1u)) >> 16;
    float r = v - __uint_as_float(hi << 16);
    uint32_t y = __float_as_uint(r);
    uint32_t lo = (y + 0x7FFFu + ((y >> 16) & 1u)) >> 16;
    return (hi << 16) | lo;
}

// ---------------------------------------------------------------------------
// Pass 1: per-chunk per-segment histogram
__global__ void k_hist(const int* __restrict__ seg, int* __restrict__ hist) {
    __shared__ int cnt[NSEG];
    int blk = blockIdx.x;
    int b = blk / NCH, ch = blk % NCH;
    int tid = threadIdx.x;
    if (tid < NSEG) cnt[tid] = 0;
    __syncthreads();
    int s = seg[(size_t)b * PIX + ch * CHSZ + tid];
    atomicAdd(&cnt[s], 1);
    __syncthreads();
    if (tid < NSEG) hist[(size_t)blk * NSEG + tid] = cnt[tid];
}

// ---------------------------------------------------------------------------
// Pass 2: exclusive prefix over chunks per (b,s), one thread per (b,s)
// (coalesced: consecutive threads = consecutive s). Totals -> counts[].
__global__ void k_scan(int* __restrict__ hist, int* __restrict__ counts) {
    int i = blockIdx.x * blockDim.x + threadIdx.x;
    if (i >= BATCH * NSEG) return;
    int b = i / NSEG, s = i % NSEG;
    int run = 0;
    for (int c = 0; c < NCH; ++c) {
        size_t idx = ((size_t)b * NCH + c) * NSEG + s;
        int t = hist[idx];
        hist[idx] = run;
        run += t;
    }
    counts[i] = run;
}

// ---------------------------------------------------------------------------
// Pass 2b: zero only the unwritten tail of each A row: [3*min(cnt,400), 1216).
__global__ void k_ztail(const int* __restrict__ counts, uint32_t* __restrict__ Apair) {
    int row = blockIdx.x * 4 + (threadIdx.x >> 6);
    int lane = threadIdx.x & 63;
    int cnt = counts[row];
    int start = 3 * min(cnt, MAXP);
    uint32_t* p = Apair + (size_t)row * KP4;
    for (int i = start + lane; i < KP4; i += 64) p[i] = 0u;
}

// ---------------------------------------------------------------------------
// Pass 3: stable rank via ballot-match + cross-wave LDS totals; scatter packed
// bf16 hi/lo pairs as one dwordx3 per pixel at kappa = 3r + c.
__global__ void k_scatter(const float* __restrict__ img,
                          const int* __restrict__ seg,
                          const int* __restrict__ offs,
                          uint32_t* __restrict__ Apair) {
    __shared__ int soff[NSEG];
    __shared__ int wcnt[8][NSEG];
    int wg = blockIdx.x;
    int b = wg / NCH, ch = wg % NCH;
    int tid = threadIdx.x;
    int lane = tid & 63, wid = tid >> 6;

    for (int i = tid; i < 8 * NSEG; i += CHSZ) ((int*)wcnt)[i] = 0;
    if (tid < NSEG) soff[tid] = offs[(size_t)wg * NSEG + tid];
    __syncthreads();

    int p = ch * CHSZ + tid;
    int sv = seg[(size_t)b * PIX + p];

    // ballot-based match_any over the 8 bits of sv (NSEG=196 < 256)
    uint64_t m = ~0ull;
    #pragma unroll
    for (int bit = 0; bit < 8; ++bit) {
        uint64_t bal = __ballot((sv >> bit) & 1);
        m &= ((sv >> bit) & 1) ? bal : ~bal;
    }
    int before = __popcll(m & ((1ull << lane) - 1ull));
    int first  = __builtin_ctzll(m);
    if (lane == first) wcnt[wid][sv] = __popcll(m);
    __syncthreads();

    int base = soff[sv];
    for (int w2 = 0; w2 < wid; ++w2) base += wcnt[w2][sv];  // wid wave-uniform
    int r = base + before;

    if (r < MAXP) {
        const float* ib = img + (size_t)b * CHN * PIX + p;
        uint32_t* dst = Apair + (size_t)(b * NSEG + sv) * KP4 + 3 * r;
        uint32_t v0 = packhl(ib[0]);
        uint32_t v1 = packhl(ib[PIX]);
        uint32_t v2 = packhl(ib[2 * PIX]);
        dst[0] = v0; dst[1] = v1; dst[2] = v2;
    }
}

// ---------------------------------------------------------------------------
// Pass 4: W [1200][768] fp32 -> Wt [768][KP4] packed bf16 hi/lo, transposed,
// with the kappa K-permutation.
__global__ void k_wprep(const float* __restrict__ W, uint32_t* __restrict__ Wt) {
    __shared__ float t[32][33];
    int kt = blockIdx.x, nt = blockIdx.y;
    int tid = threadIdx.x;
    int tx = tid & 31, ty = tid >> 5;  // 32 x 8
    #pragma unroll
    for (int i = 0; i < 4; ++i) {
        int k = kt * 32 + i * 8 + ty;
        int n = nt * 32 + tx;
        t[i * 8 + ty][tx] = (k < KDIM) ? W[(size_t)k * DN + n] : 0.0f;
    }
    __syncthreads();
    #pragma unroll
    for (int i = 0; i < 4; ++i) {
        int n = nt * 32 + i * 8 + ty;
        int k = kt * 32 + tx;
        int kap = (k < KDIM) ? 3 * (k % MAXP) + (k / MAXP) : k;
        Wt[(size_t)n * KP4 + kap] = packhl(t[tx][i * 8 + ty]);
    }
}

// ---------------------------------------------------------------------------
// Pass 5: pair-direct MFMA GEMM (32x32x16 shape), exact 4-term split product:
//   pass1: mfma(A_raw,  B_raw ) = sum(hi*hi' + lo*lo')
//   pass2: mfma(A_raw, rot16(B)) = sum(hi*lo' + lo*hi')
// 128x128 tile, 256 threads (4 waves 2x2, wave tile 64x64 -> LDS/MFMA
// balanced at 512:512 cyc/kt/CU), double-buffered LDS via global_load_lds,
// XOR slot swizzle, counted-vmcnt raw-barrier pipeline (T4), XCD-grouped grid.
__device__ __forceinline__ void gld16(const void* g, void* l) {
    __builtin_amdgcn_global_load_lds(
        (const __attribute__((address_space(1))) unsigned int*)g,
        (__attribute__((address_space(3))) unsigned int*)l, 16, 0, 0);
}

#define NWG 588   // 98 bm * 6 bn
__global__ __launch_bounds__(256, 2) void k_gemm(const uint32_t* __restrict__ A,
                                                 const uint32_t* __restrict__ Bw,
                                                 const float* __restrict__ bias,
                                                 float* __restrict__ Co) {
    __shared__ uint32_t lds[2][2][128 * 32];   // [buf][A|B][row*32 + word]
    // bijective XCD-grouping swizzle (m204): q=73, rm=4
    int j = blockIdx.x;
    int xcd = j & 7, sl = j >> 3;
    const int q = NWG / 8, rm = NWG % 8;
    int wgid = (xcd < rm ? xcd * (q + 1) : rm * (q + 1) + (xcd - rm) * q) + sl;
    int bm = wgid / 6, bn = wgid % 6;

    int tid = threadIdx.x;
    int lane = tid & 63, w = tid >> 6;    // 4 waves
    int wm = w >> 1, wn = w & 1;          // 2x2; wave tile 64 rows x 64 cols
    int l31 = lane & 31, kh = lane >> 5;  // MFMA row-in-block / k-half

    const uint32_t* Ab = A + (size_t)(bm * 128) * KP4;
    const uint32_t* Bb = Bw + (size_t)(bn * 128) * KP4;

    f32x16 acc[2][2] = {};

    // staging: per wave 4 gld16 per matrix; instr q covers rows (q*4+w)*8..+7
    int sr = lane >> 3, ss = lane & 7;

#define STAGE(buf, kt) do {                                                   \
    _Pragma("unroll")                                                         \
    for (int qq = 0; qq < 4; ++qq) {                                          \
        int rb = (qq * 4 + w) * 8;                                            \
        int row = rb + sr;                                                    \
        int sp = ss ^ (row & 7);                                              \
        gld16(Ab + (size_t)row * KP4 + (size_t)(kt) * 32 + sp * 4,            \
              &lds[buf][0][rb * 32]);                                         \
        gld16(Bb + (size_t)row * KP4 + (size_t)(kt) * 32 + sp * 4,            \
              &lds[buf][1][rb * 32]);                                         \
    }                                                                         \
} while (0)

    STAGE(0, 0);     // 8 loads in flight

    int cur = 0;
    for (int kt = 0; kt < NTK; ++kt) {
        if (kt + 1 < NTK) {
            STAGE(cur ^ 1, kt + 1);                      // +8 (16 outstanding)
            asm volatile("s_waitcnt vmcnt(8)" ::: "memory");  // tile-kt landed
        } else {
            asm volatile("s_waitcnt vmcnt(0)" ::: "memory");
        }
        __builtin_amdgcn_s_barrier();   // all waves' tile-kt loads visible

        #pragma unroll
        for (int ks = 0; ks < 4; ++ks) {   // 4 x (K=16) MFMA steps per kt
            union { uint4v u; short8 s; } af[2], bf[2], bs[2];
            #pragma unroll
            for (int mi = 0; mi < 2; ++mi) {
                int row = wm * 64 + mi * 32 + l31;
                int slot = (ks * 2 + kh) ^ (row & 7);
                af[mi].u = *(const uint4v*)&lds[cur][0][row * 32 + slot * 4];
            }
            #pragma unroll
            for (int ni = 0; ni < 2; ++ni) {
                int row = wn * 64 + ni * 32 + l31;
                int slot = (ks * 2 + kh) ^ (row & 7);
                bf[ni].u = *(const uint4v*)&lds[cur][1][row * 32 + slot * 4];
                bs[ni].u.x = (bf[ni].u.x >> 16) | (bf[ni].u.x << 16);
                bs[ni].u.y = (bf[ni].u.y >> 16) | (bf[ni].u.y << 16);
                bs[ni].u.z = (bf[ni].u.z >> 16) | (bf[ni].u.z << 16);
                bs[ni].u.w = (bf[ni].u.w >> 16) | (bf[ni].u.w << 16);
            }
            #pragma unroll
            for (int mi = 0; mi < 2; ++mi)
                #pragma unroll
                for (int ni = 0; ni < 2; ++ni) {
                    acc[mi][ni] = __builtin_amdgcn_mfma_f32_32x32x16_bf16(
                        af[mi].s, bf[ni].s, acc[mi][ni], 0, 0, 0);
                    acc[mi][ni] = __builtin_amdgcn_mfma_f32_32x32x16_bf16(
                        af[mi].s, bs[ni].s, acc[mi][ni], 0, 0, 0);
                }
        }

        __builtin_amdgcn_s_barrier();   // all waves done reading buf cur
        cur ^= 1;
    }
#undef STAGE

    // C/D 32x32 layout: col = lane&31, row = (reg&3) + 8*(reg>>2) + 4*(lane>>5)
    #pragma unroll
    for (int ni = 0; ni < 2; ++ni) {
        int col = bn * 128 + wn * 64 + ni * 32 + l31;
        float bv = bias[col];
        #pragma unroll
        for (int mi = 0; mi < 2; ++mi) {
            int rb = bm * 128 + wm * 64 + mi * 32 + 4 * kh;
            #pragma unroll
            for (int reg = 0; reg < 16; ++reg) {
                int row = rb + (reg & 3) + 8 * (reg >> 2);
                Co[(size_t)row * DN + col] = acc[mi][ni][reg] + bv;
            }
        }
    }
}

// ---------------------------------------------------------------------------
extern "C" void kernel_launch(void* const* d_in, const int* in_sizes, int n_in,
                              void* d_out, int out_size, void* d_ws, size_t ws_size,
                              hipStream_t stream) {
    const float* img = (const float*)d_in[0];
    const int*   seg = (const int*)d_in[1];
    const float* W   = (const float*)d_in[2];
    const float* bia = (const float*)d_in[3];
    float* out = (float*)d_out;

    const size_t APAIR_BYTES = (size_t)MROWS * KP4 * 4;            // 61,014,016
    const size_t HIST_BYTES  = (size_t)BATCH * NCH * NSEG * 4;     //  4,917,248
    uint32_t* Apair  = (uint32_t*)d_ws;
    int*      hist   = (int*)((char*)d_ws + APAIR_BYTES);
    int*      counts = (int*)((char*)d_ws + APAIR_BYTES + HIST_BYTES);
    // Wt overlaps hist: hist is dead after k_scatter; k_wprep runs after it.
    uint32_t* Wt     = (uint32_t*)hist;

    k_hist<<<BATCH * NCH, CHSZ, 0, stream>>>(seg, hist);
    k_scan<<<(BATCH * NSEG + 255) / 256, 256, 0, stream>>>(hist, counts);
    k_ztail<<<MROWS / 4, 256, 0, stream>>>(counts, Apair);
    k_scatter<<<BATCH * NCH, CHSZ, 0, stream>>>(img, seg, hist, Apair);
    k_wprep<<<dim3(NTK, DN / 32), 256, 0, stream>>>(W, Wt);

    k_gemm<<<NWG, 256, 0, stream>>>(Apair, Wt, bia, out);
}

// Round 7
// 232.751 us; speedup vs baseline: 1.0982x; 1.0982x over previous
//
#include <hip/hip_runtime.h>
#include <hip/hip_bf16.h>
#include <stdint.h>

// Problem constants
#define BATCH 64
#define CHN 3
#define HH 224
#define WW 224
#define PIX (HH * WW)          // 50176
#define NSEG 196
#define MAXP 400
#define KDIM (CHN * MAXP)      // 1200
#define DN 768

#define KP4 1216               // K in u32 hi/lo pairs per row (padded)
#define NTK 38                 // 1216 / 32 K-steps
#define MROWS (BATCH * NSEG)   // 12544

// chunking for stable rank assignment
#define CHSZ 512
#define NCH (PIX / CHSZ)       // 98

typedef short short8 __attribute__((ext_vector_type(8)));
typedef float f32x4 __attribute__((ext_vector_type(4)));
typedef unsigned int uint4v __attribute__((ext_vector_type(4)));

// K permutation: k = c*MAXP + r -> kappa = 3r + c (scatter writes one dwordx3
// per pixel). Applied to BOTH A and W; dot product invariant.

// pack fp32 -> (bf16_hi << 16) | bf16_lo  with hi = rn(v), lo = rn(v - hi)
// As a bf16x2 word: (elem0=lo, elem1=hi). Raw MFMA gives lo*lo'+hi*hi';
// vs rot16'd B gives lo*hi'+hi*lo' -> 2 passes = exact 4-term product.
__device__ __forceinline__ uint32_t packhl(float v) {
    uint32_t x = __float_as_uint(v);
    uint32_t hi = (x + 0x7FFFu + ((x >> 16) & 1u)) >> 16;
    float r = v - __uint_as_float(hi << 16);
    uint32_t y = __float_as_uint(r);
    uint32_t lo = (y + 0x7FFFu + ((y >> 16) & 1u)) >> 16;
    return (hi << 16) | lo;
}

// ---------------------------------------------------------------------------
// Pass 1: per-chunk per-segment histogram
__global__ void k_hist(const int* __restrict__ seg, int* __restrict__ hist) {
    __shared__ int cnt[NSEG];
    int blk = blockIdx.x;
    int b = blk / NCH, ch = blk % NCH;
    int tid = threadIdx.x;
    if (tid < NSEG) cnt[tid] = 0;
    __syncthreads();
    int s = seg[(size_t)b * PIX + ch * CHSZ + tid];
    atomicAdd(&cnt[s], 1);
    __syncthreads();
    if (tid < NSEG) hist[(size_t)blk * NSEG + tid] = cnt[tid];
}

// ---------------------------------------------------------------------------
// Pass 2: exclusive prefix over chunks per (b,s), one thread per (b,s)
// (coalesced: consecutive threads = consecutive s). Totals -> counts[].
__global__ void k_scan(int* __restrict__ hist, int* __restrict__ counts) {
    int i = blockIdx.x * blockDim.x + threadIdx.x;
    if (i >= BATCH * NSEG) return;
    int b = i / NSEG, s = i % NSEG;
    int run = 0;
    for (int c = 0; c < NCH; ++c) {
        size_t idx = ((size_t)b * NCH + c) * NSEG + s;
        int t = hist[idx];
        hist[idx] = run;
        run += t;
    }
    counts[i] = run;
}

// ---------------------------------------------------------------------------
// Pass 3: stable rank via ballot-match + cross-wave LDS totals; scatter packed
// bf16 hi/lo pairs as one dwordx3 per pixel at kappa = 3r + c.
// blockIdx XCD-grouped by batch (6272 = 8*784, bijective): each batch's
// ~1 MB Apair slab accumulates within one XCD's L2 -> full-line HBM writes.
__global__ void k_scatter(const float* __restrict__ img,
                          const int* __restrict__ seg,
                          const int* __restrict__ offs,
                          uint32_t* __restrict__ Apair) {
    __shared__ int soff[NSEG];
    __shared__ int wcnt[8][NSEG];
    int blk0 = blockIdx.x;
    int wg = (blk0 & 7) * (BATCH * NCH / 8) + (blk0 >> 3);  // bijective
    int b = wg / NCH, ch = wg % NCH;
    int tid = threadIdx.x;
    int lane = tid & 63, wid = tid >> 6;

    for (int i = tid; i < 8 * NSEG; i += CHSZ) ((int*)wcnt)[i] = 0;
    if (tid < NSEG) soff[tid] = offs[(size_t)wg * NSEG + tid];
    __syncthreads();

    int p = ch * CHSZ + tid;
    int sv = seg[(size_t)b * PIX + p];

    // ballot-based match_any over the 8 bits of sv (NSEG=196 < 256)
    uint64_t m = ~0ull;
    #pragma unroll
    for (int bit = 0; bit < 8; ++bit) {
        uint64_t bal = __ballot((sv >> bit) & 1);
        m &= ((sv >> bit) & 1) ? bal : ~bal;
    }
    int before = __popcll(m & ((1ull << lane) - 1ull));
    int first  = __builtin_ctzll(m);
    if (lane == first) wcnt[wid][sv] = __popcll(m);
    __syncthreads();

    int base = soff[sv];
    for (int w2 = 0; w2 < wid; ++w2) base += wcnt[w2][sv];  // wid wave-uniform
    int r = base + before;

    if (r < MAXP) {
        const float* ib = img + (size_t)b * CHN * PIX + p;
        uint32_t* dst = Apair + (size_t)(b * NSEG + sv) * KP4 + 3 * r;
        uint32_t v0 = packhl(ib[0]);
        uint32_t v1 = packhl(ib[PIX]);
        uint32_t v2 = packhl(ib[2 * PIX]);
        dst[0] = v0; dst[1] = v1; dst[2] = v2;
    }
}

// ---------------------------------------------------------------------------
// Pass 4 (fused): blocks [0,912): W-prep transpose+pack+kappa-permute;
// blocks [912,4048): zero unwritten A-row tails [3*min(cnt,400), 1216).
// Must run AFTER k_scatter (Wt overlaps hist, which scatter reads).
#define WPREP_BLKS (NTK * (DN / 32))   // 912
__global__ void k_prep(const float* __restrict__ W, uint32_t* __restrict__ Wt,
                       const int* __restrict__ counts, uint32_t* __restrict__ Apair) {
    int blk = blockIdx.x;
    int tid = threadIdx.x;
    if (blk >= WPREP_BLKS) {
        int row = (blk - WPREP_BLKS) * 4 + (tid >> 6);
        int lane = tid & 63;
        int cnt = counts[row];
        int start = 3 * min(cnt, MAXP);
        uint32_t* p = Apair + (size_t)row * KP4;
        for (int i = start + lane; i < KP4; i += 64) p[i] = 0u;
        return;
    }
    __shared__ float t[32][33];
    int kt = blk % NTK, nt = blk / NTK;
    int tx = tid & 31, ty = tid >> 5;  // 32 x 8
    #pragma unroll
    for (int i = 0; i < 4; ++i) {
        int k = kt * 32 + i * 8 + ty;
        int n = nt * 32 + tx;
        t[i * 8 + ty][tx] = (k < KDIM) ? W[(size_t)k * DN + n] : 0.0f;
    }
    __syncthreads();
    #pragma unroll
    for (int i = 0; i < 4; ++i) {
        int n = nt * 32 + i * 8 + ty;
        int k = kt * 32 + tx;
        int kap = (k < KDIM) ? 3 * (k % MAXP) + (k / MAXP) : k;
        Wt[(size_t)n * KP4 + kap] = packhl(t[tx][i * 8 + ty]);
    }
}

// ---------------------------------------------------------------------------
// Pass 5: pair-direct MFMA GEMM (16x16x32), exact 4-term split product:
//   pass1: mfma(A_raw,  B_raw ) = sum(hi*hi' + lo*lo')
//   pass2: mfma(A_raw, rot16(B)) = sum(hi*lo' + lo*hi')
// 128x128 tile, 512 threads (8 waves 2x4, wave tile 64x32), BK=32 pairs,
// double-buffered LDS via global_load_lds, XOR slot swizzle, XCD-grouped grid.
// T4 pipeline: raw s_barrier + counted vmcnt(4) -- next tile's 4 loads stay
// in flight across the barrier (no full drain per K-step).
__device__ __forceinline__ void gld16(const void* g, void* l) {
    __builtin_amdgcn_global_load_lds(
        (const __attribute__((address_space(1))) unsigned int*)g,
        (__attribute__((address_space(3))) unsigned int*)l, 16, 0, 0);
}

#define NWG 588   // 98 bm * 6 bn
__global__ __launch_bounds__(512, 4) void k_gemm(const uint32_t* __restrict__ A,
                                                 const uint32_t* __restrict__ Bw,
                                                 const float* __restrict__ bias,
                                                 float* __restrict__ Co) {
    __shared__ uint32_t lds[2][2][128 * 32];   // [buf][A|B][row*32 + slotword]
    // bijective XCD-grouping swizzle (m204): q=73, rm=4
    int j = blockIdx.x;
    int xcd = j & 7, sl = j >> 3;
    const int q = NWG / 8, rm = NWG % 8;
    int wgid = (xcd < rm ? xcd * (q + 1) : rm * (q + 1) + (xcd - rm) * q) + sl;
    int bm = wgid / 6, bn = wgid % 6;

    int tid = threadIdx.x;
    int lane = tid & 63, w = tid >> 6;    // 8 waves
    int wm = w >> 2, wn = w & 3;          // 2 x 4; wave tile 64 rows x 32 cols
    int r15 = lane & 15, kb = lane >> 4;

    // staging: each thread loads 2x16B per matrix; rows w*8..w*8+7 (+64)
    int srow = w * 8 + (lane >> 3);
    int sslot = lane & 7;
    int ssw = sslot ^ (srow & 7);         // pre-swizzled source slot
    size_t aoff0 = (size_t)srow * KP4 + ssw * 4;
    size_t aoff1 = (size_t)(srow + 64) * KP4 + ssw * 4;  // (srow+64)&7 == srow&7

    const uint32_t* Ab = A + (size_t)(bm * 128) * KP4;
    const uint32_t* Bb = Bw + (size_t)(bn * 128) * KP4;

    f32x4 acc[4][2] = {};

#define STAGE(buf, kt) do {                                        \
    gld16(Ab + aoff0 + (size_t)(kt) * 32, &lds[buf][0][w * 256]);  \
    gld16(Ab + aoff1 + (size_t)(kt) * 32, &lds[buf][0][2048 + w * 256]); \
    gld16(Bb + aoff0 + (size_t)(kt) * 32, &lds[buf][1][w * 256]);  \
    gld16(Bb + aoff1 + (size_t)(kt) * 32, &lds[buf][1][2048 + w * 256]); \
} while (0)

    STAGE(0, 0);     // 4 loads in flight (per wave)

    int cur = 0;
    for (int kt = 0; kt < NTK; ++kt) {
        if (kt + 1 < NTK) {
            STAGE(cur ^ 1, kt + 1);                           // 8 outstanding
            asm volatile("s_waitcnt vmcnt(4)" ::: "memory");  // tile-kt landed
        } else {
            asm volatile("s_waitcnt vmcnt(0)" ::: "memory");
        }
        __builtin_amdgcn_s_barrier();   // all waves' tile-kt loads visible

        #pragma unroll
        for (int sg = 0; sg < 2; ++sg) {
            union { uint4v u; short8 s; } af[4];
            #pragma unroll
            for (int mi = 0; mi < 4; ++mi) {
                int row = wm * 64 + mi * 16 + r15;
                int slot = (sg * 4 + kb) ^ (row & 7);
                af[mi].u = *(const uint4v*)&lds[cur][0][row * 32 + slot * 4];
            }
            #pragma unroll
            for (int ni = 0; ni < 2; ++ni) {
                int row = wn * 32 + ni * 16 + r15;
                int slot = (sg * 4 + kb) ^ (row & 7);
                union { uint4v u; short8 s; } bf, bs;
                bf.u = *(const uint4v*)&lds[cur][1][row * 32 + slot * 4];
                bs.u.x = (bf.u.x >> 16) | (bf.u.x << 16);
                bs.u.y = (bf.u.y >> 16) | (bf.u.y << 16);
                bs.u.z = (bf.u.z >> 16) | (bf.u.z << 16);
                bs.u.w = (bf.u.w >> 16) | (bf.u.w << 16);
                #pragma unroll
                for (int mi = 0; mi < 4; ++mi) {
                    acc[mi][ni] = __builtin_amdgcn_mfma_f32_16x16x32_bf16(
                        af[mi].s, bf.s, acc[mi][ni], 0, 0, 0);
                    acc[mi][ni] = __builtin_amdgcn_mfma_f32_16x16x32_bf16(
                        af[mi].s, bs.s, acc[mi][ni], 0, 0, 0);
                }
            }
        }

        __builtin_amdgcn_s_barrier();   // all waves done reading buf cur
        cur ^= 1;
    }
#undef STAGE

    // C row = bm*128 + wm*64 + mi*16 + kb*4 + e; col = bn*128 + wn*32 + ni*16 + r15
    #pragma unroll
    for (int ni = 0; ni < 2; ++ni) {
        int col = bn * 128 + wn * 32 + ni * 16 + r15;
        float bv = bias[col];
        #pragma unroll
        for (int mi = 0; mi < 4; ++mi) {
            int rbase = bm * 128 + wm * 64 + mi * 16 + kb * 4;
            #pragma unroll
            for (int e = 0; e < 4; ++e)
                Co[(size_t)(rbase + e) * DN + col] = acc[mi][ni][e] + bv;
        }
    }
}

// ---------------------------------------------------------------------------
extern "C" void kernel_launch(void* const* d_in, const int* in_sizes, int n_in,
                              void* d_out, int out_size, void* d_ws, size_t ws_size,
                              hipStream_t stream) {
    const float* img = (const float*)d_in[0];
    const int*   seg = (const int*)d_in[1];
    const float* W   = (const float*)d_in[2];
    const float* bia = (const float*)d_in[3];
    float* out = (float*)d_out;

    const size_t APAIR_BYTES = (size_t)MROWS * KP4 * 4;            // 61,014,016
    const size_t HIST_BYTES  = (size_t)BATCH * NCH * NSEG * 4;     //  4,917,248
    uint32_t* Apair  = (uint32_t*)d_ws;
    int*      hist   = (int*)((char*)d_ws + APAIR_BYTES);
    int*      counts = (int*)((char*)d_ws + APAIR_BYTES + HIST_BYTES);
    // Wt overlaps hist: hist is dead after k_scatter; k_prep runs after it.
    uint32_t* Wt     = (uint32_t*)hist;

    k_hist<<<BATCH * NCH, CHSZ, 0, stream>>>(seg, hist);
    k_scan<<<(BATCH * NSEG + 255) / 256, 256, 0, stream>>>(hist, counts);
    k_scatter<<<BATCH * NCH, CHSZ, 0, stream>>>(img, seg, hist, Apair);
    k_prep<<<WPREP_BLKS + MROWS / 4, 256, 0, stream>>>(W, Wt, counts, Apair);

    k_gemm<<<NWG, 512, 0, stream>>>(Apair, Wt, bia, out);
}

// Round 9
// 228.049 us; speedup vs baseline: 1.1208x; 1.0206x over previous
//
#include <hip/hip_runtime.h>
#include <hip/hip_bf16.h>
#include <stdint.h>

// Problem constants
#define BATCH 64
#define CHN 3
#define HH 224
#define WW 224
#define PIX (HH * WW)          // 50176
#define NSEG 196
#define MAXP 400
#define KDIM (CHN * MAXP)      // 1200
#define DN 768

#define KP4 1216               // K in u32 hi/lo pairs per row (padded)
#define BKP 16                 // pairs per K-step (LDS tile depth)
#define NTK (KP4 / BKP)        // 76
#define MROWS (BATCH * NSEG)   // 12544

// chunking for stable rank assignment
#define CHSZ 512
#define NCH (PIX / CHSZ)       // 98

typedef short short8 __attribute__((ext_vector_type(8)));
typedef float f32x4 __attribute__((ext_vector_type(4)));
typedef unsigned int uint4v __attribute__((ext_vector_type(4)));

// K permutation: k = c*MAXP + r -> kappa = 3r + c (scatter writes one dwordx3
// per pixel). Applied to BOTH A and W; dot product invariant.

// pack fp32 -> (bf16_hi << 16) | bf16_lo  with hi = rn(v), lo = rn(v - hi)
// As a bf16x2 word: (elem0=lo, elem1=hi). Raw MFMA gives lo*lo'+hi*hi';
// vs rot16'd B gives lo*hi'+hi*lo' -> 2 passes = exact 4-term product.
__device__ __forceinline__ uint32_t packhl(float v) {
    uint32_t x = __float_as_uint(v);
    uint32_t hi = (x + 0x7FFFu + ((x >> 16) & 1u)) >> 16;
    float r = v - __uint_as_float(hi << 16);
    uint32_t y = __float_as_uint(r);
    uint32_t lo = (y + 0x7FFFu + ((y >> 16) & 1u)) >> 16;
    return (hi << 16) | lo;
}

// ---------------------------------------------------------------------------
// Pass 1: per-chunk per-segment histogram
__global__ void k_hist(const int* __restrict__ seg, int* __restrict__ hist) {
    __shared__ int cnt[NSEG];
    int blk = blockIdx.x;
    int b = blk / NCH, ch = blk % NCH;
    int tid = threadIdx.x;
    if (tid < NSEG) cnt[tid] = 0;
    __syncthreads();
    int s = seg[(size_t)b * PIX + ch * CHSZ + tid];
    atomicAdd(&cnt[s], 1);
    __syncthreads();
    if (tid < NSEG) hist[(size_t)blk * NSEG + tid] = cnt[tid];
}

// ---------------------------------------------------------------------------
// Pass 2: exclusive prefix over chunks per (b,s), one thread per (b,s)
// (coalesced: consecutive threads = consecutive s). Totals -> counts[].
__global__ void k_scan(int* __restrict__ hist, int* __restrict__ counts) {
    int i = blockIdx.x * blockDim.x + threadIdx.x;
    if (i >= BATCH * NSEG) return;
    int b = i / NSEG, s = i % NSEG;
    int run = 0;
    for (int c = 0; c < NCH; ++c) {
        size_t idx = ((size_t)b * NCH + c) * NSEG + s;
        int t = hist[idx];
        hist[idx] = run;
        run += t;
    }
    counts[i] = run;
}

// ---------------------------------------------------------------------------
// Pass 3: stable rank via ballot-match + cross-wave LDS totals; scatter packed
// bf16 hi/lo pairs as one dwordx3 per pixel at kappa = 3r + c.
// blockIdx XCD-grouped by batch (6272 = 8*784, bijective).
__global__ void k_scatter(const float* __restrict__ img,
                          const int* __restrict__ seg,
                          const int* __restrict__ offs,
                          uint32_t* __restrict__ Apair) {
    __shared__ int soff[NSEG];
    __shared__ int wcnt[8][NSEG];
    int blk0 = blockIdx.x;
    int wg = (blk0 & 7) * (BATCH * NCH / 8) + (blk0 >> 3);  // bijective
    int b = wg / NCH, ch = wg % NCH;
    int tid = threadIdx.x;
    int lane = tid & 63, wid = tid >> 6;

    for (int i = tid; i < 8 * NSEG; i += CHSZ) ((int*)wcnt)[i] = 0;
    if (tid < NSEG) soff[tid] = offs[(size_t)wg * NSEG + tid];
    __syncthreads();

    int p = ch * CHSZ + tid;
    int sv = seg[(size_t)b * PIX + p];

    // ballot-based match_any over the 8 bits of sv (NSEG=196 < 256)
    uint64_t m = ~0ull;
    #pragma unroll
    for (int bit = 0; bit < 8; ++bit) {
        uint64_t bal = __ballot((sv >> bit) & 1);
        m &= ((sv >> bit) & 1) ? bal : ~bal;
    }
    int before = __popcll(m & ((1ull << lane) - 1ull));
    int first  = __builtin_ctzll(m);
    if (lane == first) wcnt[wid][sv] = __popcll(m);
    __syncthreads();

    int base = soff[sv];
    for (int w2 = 0; w2 < wid; ++w2) base += wcnt[w2][sv];  // wid wave-uniform
    int r = base + before;

    if (r < MAXP) {
        const float* ib = img + (size_t)b * CHN * PIX + p;
        uint32_t* dst = Apair + (size_t)(b * NSEG + sv) * KP4 + 3 * r;
        uint32_t v0 = packhl(ib[0]);
        uint32_t v1 = packhl(ib[PIX]);
        uint32_t v2 = packhl(ib[2 * PIX]);
        dst[0] = v0; dst[1] = v1; dst[2] = v2;
    }
}

// ---------------------------------------------------------------------------
// Pass 4 (fused): blocks [0,912): W-prep transpose+pack+kappa-permute;
// blocks [912,4048): zero unwritten A-row tails [3*min(cnt,400), 1216).
// Must run AFTER k_scatter (Wt overlaps hist, which scatter reads).
#define WPREP_BLKS (38 * (DN / 32))   // 912  (38 k-tiles of 32)
__global__ void k_prep(const float* __restrict__ W, uint32_t* __restrict__ Wt,
                       const int* __restrict__ counts, uint32_t* __restrict__ Apair) {
    int blk = blockIdx.x;
    int tid = threadIdx.x;
    if (blk >= WPREP_BLKS) {
        int row = (blk - WPREP_BLKS) * 4 + (tid >> 6);
        int lane = tid & 63;
        int cnt = counts[row];
        int start = 3 * min(cnt, MAXP);
        uint32_t* p = Apair + (size_t)row * KP4;
        for (int i = start + lane; i < KP4; i += 64) p[i] = 0u;
        return;
    }
    __shared__ float t[32][33];
    int kt = blk % 38, nt = blk / 38;
    int tx = tid & 31, ty = tid >> 5;  // 32 x 8
    #pragma unroll
    for (int i = 0; i < 4; ++i) {
        int k = kt * 32 + i * 8 + ty;
        int n = nt * 32 + tx;
        t[i * 8 + ty][tx] = (k < KDIM) ? W[(size_t)k * DN + n] : 0.0f;
    }
    __syncthreads();
    #pragma unroll
    for (int i = 0; i < 4; ++i) {
        int n = nt * 32 + i * 8 + ty;
        int k = kt * 32 + tx;
        int kap = (k < KDIM) ? 3 * (k % MAXP) + (k / MAXP) : k;
        Wt[(size_t)n * KP4 + kap] = packhl(t[tx][i * 8 + ty]);
    }
}

// ---------------------------------------------------------------------------
// Pass 5: pair-direct MFMA GEMM (16x16x32), exact 4-term split product:
//   pass1: mfma(A_raw,  B_raw ) = sum(hi*hi' + lo*lo')
//   pass2: mfma(A_raw, rot16(B)) = sum(hi*lo' + lo*hi')
// 128x128 tile, 512 threads (8 waves 2x4, wave tile 64x32), BKP=16 pairs,
// LDS 32 KB total -> 4 independent blocks/CU (2048 thr = CU max): cross-block
// phase interleave feeds the MFMA pipe while sibling blocks sit at barriers.
__device__ __forceinline__ void gld16(const void* g, void* l) {
    __builtin_amdgcn_global_load_lds(
        (const __attribute__((address_space(1))) unsigned int*)g,
        (__attribute__((address_space(3))) unsigned int*)l, 16, 0, 0);
}

#define NWG 588   // 98 bm * 6 bn
__global__ __launch_bounds__(512, 8) void k_gemm(const uint32_t* __restrict__ A,
                                                 const uint32_t* __restrict__ Bw,
                                                 const float* __restrict__ bias,
                                                 float* __restrict__ Co) {
    __shared__ uint32_t lds[2][2][128 * BKP];  // [buf][A|B][row*16 + word] 32 KB
    // bijective XCD-grouping swizzle (m204): q=73, rm=4
    int j = blockIdx.x;
    int xcd = j & 7, sl = j >> 3;
    const int q = NWG / 8, rm = NWG % 8;
    int wgid = (xcd < rm ? xcd * (q + 1) : rm * (q + 1) + (xcd - rm) * q) + sl;
    int bm = wgid / 6, bn = wgid % 6;

    int tid = threadIdx.x;
    int lane = tid & 63, w = tid >> 6;    // 8 waves
    int wm = w >> 2, wn = w & 3;          // 2 x 4; wave tile 64 rows x 32 cols
    int r15 = lane & 15, kb = lane >> 4;  // frag row / k-block (slot)

    // staging: thread t covers (row = t>>2, slot = t&3); 4-slot XOR swizzle on
    // (row>>1)&3 so frag reads are <=2-way bank aliased (free, m136).
    int srow = tid >> 2;                  // 0..127
    int sslot = tid & 3;
    int sp = sslot ^ ((srow >> 1) & 3);   // pre-swizzled source slot
    size_t goff = (size_t)srow * KP4 + sp * 4;

    const uint32_t* Ab = A + (size_t)(bm * 128) * KP4;
    const uint32_t* Bb = Bw + (size_t)(bn * 128) * KP4;

    f32x4 acc[4][2] = {};

#define STAGE(buf, kt) do {                                              \
    gld16(Ab + goff + (size_t)(kt) * BKP, &lds[buf][0][w * 256]);        \
    gld16(Bb + goff + (size_t)(kt) * BKP, &lds[buf][1][w * 256]);        \
} while (0)

    STAGE(0, 0);     // 2 loads in flight per wave

    int cur = 0;
    for (int kt = 0; kt < NTK; ++kt) {
        if (kt + 1 < NTK) {
            STAGE(cur ^ 1, kt + 1);                           // 4 outstanding
            asm volatile("s_waitcnt vmcnt(2)" ::: "memory");  // tile-kt landed
        } else {
            asm volatile("s_waitcnt vmcnt(0)" ::: "memory");
        }
        __builtin_amdgcn_s_barrier();   // all waves' tile-kt loads visible

        union { uint4v u; short8 s; } af[4];
        #pragma unroll
        for (int mi = 0; mi < 4; ++mi) {
            int row = wm * 64 + mi * 16 + r15;
            int slot = kb ^ ((row >> 1) & 3);
            af[mi].u = *(const uint4v*)&lds[cur][0][row * BKP + slot * 4];
        }
        #pragma unroll
        for (int ni = 0; ni < 2; ++ni) {
            int row = wn * 32 + ni * 16 + r15;
            int slot = kb ^ ((row >> 1) & 3);
            union { uint4v u; short8 s; } bf, bs;
            bf.u = *(const uint4v*)&lds[cur][1][row * BKP + slot * 4];
            bs.u.x = (bf.u.x >> 16) | (bf.u.x << 16);
            bs.u.y = (bf.u.y >> 16) | (bf.u.y << 16);
            bs.u.z = (bf.u.z >> 16) | (bf.u.z << 16);
            bs.u.w = (bf.u.w >> 16) | (bf.u.w << 16);
            #pragma unroll
            for (int mi = 0; mi < 4; ++mi) {
                acc[mi][ni] = __builtin_amdgcn_mfma_f32_16x16x32_bf16(
                    af[mi].s, bf.s, acc[mi][ni], 0, 0, 0);
                acc[mi][ni] = __builtin_amdgcn_mfma_f32_16x16x32_bf16(
                    af[mi].s, bs.s, acc[mi][ni], 0, 0, 0);
            }
        }

        __builtin_amdgcn_s_barrier();   // all waves done reading buf cur
        cur ^= 1;
    }
#undef STAGE

    // C row = bm*128 + wm*64 + mi*16 + kb*4 + e; col = bn*128 + wn*32 + ni*16 + r15
    #pragma unroll
    for (int ni = 0; ni < 2; ++ni) {
        int col = bn * 128 + wn * 32 + ni * 16 + r15;
        float bv = bias[col];
        #pragma unroll
        for (int mi = 0; mi < 4; ++mi) {
            int rbase = bm * 128 + wm * 64 + mi * 16 + kb * 4;
            #pragma unroll
            for (int e = 0; e < 4; ++e)
                Co[(size_t)(rbase + e) * DN + col] = acc[mi][ni][e] + bv;
        }
    }
}

// ---------------------------------------------------------------------------
extern "C" void kernel_launch(void* const* d_in, const int* in_sizes, int n_in,
                              void* d_out, int out_size, void* d_ws, size_t ws_size,
                              hipStream_t stream) {
    const float* img = (const float*)d_in[0];
    const int*   seg = (const int*)d_in[1];
    const float* W   = (const float*)d_in[2];
    const float* bia = (const float*)d_in[3];
    float* out = (float*)d_out;

    const size_t APAIR_BYTES = (size_t)MROWS * KP4 * 4;            // 61,014,016
    const size_t HIST_BYTES  = (size_t)BATCH * NCH * NSEG * 4;     //  4,917,248
    uint32_t* Apair  = (uint32_t*)d_ws;
    int*      hist   = (int*)((char*)d_ws + APAIR_BYTES);
    int*      counts = (int*)((char*)d_ws + APAIR_BYTES + HIST_BYTES);
    // Wt overlaps hist: hist is dead after k_scatter; k_prep runs after it.
    uint32_t* Wt     = (uint32_t*)hist;

    k_hist<<<BATCH * NCH, CHSZ, 0, stream>>>(seg, hist);
    k_scan<<<(BATCH * NSEG + 255) / 256, 256, 0, stream>>>(hist, counts);
    k_scatter<<<BATCH * NCH, CHSZ, 0, stream>>>(img, seg, hist, Apair);
    k_prep<<<WPREP_BLKS + MROWS / 4, 256, 0, stream>>>(W, Wt, counts, Apair);

    k_gemm<<<NWG, 512, 0, stream>>>(Apair, Wt, bia, out);
}